// Round 11
// baseline (152.455 us; speedup 1.0000x reference)
//
#include <hip/hip_runtime.h>
#include <hip/hip_bf16.h>

#define NB 16384
#define DIN 512
#define H1 256
#define H2 128
#define NE 18
#define NT 3
#define NGH 64
#define NETOT 14

typedef float f32x4 __attribute__((ext_vector_type(4)));
typedef short s16x8 __attribute__((ext_vector_type(8)));
typedef unsigned short u16;
typedef unsigned int u32;

__device__ __forceinline__ u16 f2bf(float f) {
    union { float f; u32 u; } v; v.f = f;
    u32 r = v.u + 0x7fffu + ((v.u >> 16) & 1u);
    return (u16)(r >> 16);
}
__device__ __forceinline__ float bf2f(u16 u) {
    union { u32 u; float f; } v; v.u = ((u32)u) << 16;
    return v.f;
}
__device__ __forceinline__ u32 cvtpk(float a, float b) {
    u32 r;
    asm("v_cvt_pk_bf16_f32 %0, %1, %2" : "=v"(r) : "v"(a), "v"(b));
    return r;
}

#define GLDS16(g, l) __builtin_amdgcn_global_load_lds((const u32*)(g), (u32*)(l), 16, 0, 0)
#define VMCNT0_BARRIER() do { asm volatile("s_waitcnt vmcnt(0)" ::: "memory"); __builtin_amdgcn_s_barrier(); } while (0)

// ---------------- prep: x cvt + ALL weight transposes, one launch ----------------
__global__ __launch_bounds__(256) void k_prep(
    const float* __restrict__ x, u16* __restrict__ xb,
    const float* __restrict__ sW1, const float* __restrict__ dW1, const float* __restrict__ tW1,
    const float* __restrict__ sW2, const float* __restrict__ dW2, const float* __restrict__ tW2,
    const float* __restrict__ gW1, u16* __restrict__ w1t, u16* __restrict__ w2t, u16* __restrict__ gw1t)
{
    __shared__ float lds[64 * 65];
    int bx = blockIdx.x;
    if (bx < 8192) {
        int i = (bx * 256 + threadIdx.x) * 4;
        float4 v = *reinterpret_cast<const float4*>(x + i);
        ushort4 o;
        o.x = f2bf(v.x); o.y = f2bf(v.y); o.z = f2bf(v.z); o.w = f2bf(v.w);
        *reinterpret_cast<ushort4*>(xb + i) = o;
        return;
    }
    int b = bx - 8192;
    const float* src; u16* dst; int K, N, k0, n0;
    if (b < 576) {
        int e = b >> 5, tile = b & 31;
        src = (e < 4) ? sW1 + (size_t)e * DIN * H1 : (e < 12) ? dW1 + (size_t)(e - 4) * DIN * H1
                                                              : tW1 + (size_t)(e - 12) * DIN * H1;
        dst = w1t + (size_t)e * H1 * DIN; K = DIN; N = H1;
        k0 = (tile >> 2) * 64; n0 = (tile & 3) * 64;
    } else if (b < 720) {
        int b2 = b - 576; int e = b2 >> 3, tile = b2 & 7;
        src = (e < 4) ? sW2 + (size_t)e * H1 * H2 : (e < 12) ? dW2 + (size_t)(e - 4) * H1 * H2
                                                             : tW2 + (size_t)(e - 12) * H1 * H2;
        dst = w2t + (size_t)e * H2 * H1; K = H1; N = H2;
        k0 = (tile >> 1) * 64; n0 = (tile & 1) * 64;
    } else {
        int b3 = b - 720; int t = b3 >> 3, tile = b3 & 7;
        src = gW1 + (size_t)t * DIN * NGH; dst = gw1t + (size_t)t * NGH * DIN; K = DIN; N = NGH;
        k0 = tile * 64; n0 = 0;
    }
    int t = threadIdx.x;
#pragma unroll
    for (int i = 0; i < 16; ++i) {
        int idx = i * 256 + t;
        int kk = idx >> 6, nn = idx & 63;
        lds[kk * 65 + nn] = src[(size_t)(k0 + kk) * N + n0 + nn];
    }
    __syncthreads();
#pragma unroll
    for (int i = 0; i < 16; ++i) {
        int idx = i * 256 + t;
        int nn = idx >> 6, kk = idx & 63;
        dst[(size_t)(n0 + nn) * K + k0 + kk] = f2bf(lds[kk * 65 + nn]);
    }
}

// ---------------- fused expert (+gate) kernel, 256x256 / 8 waves / 4-phase tiles ----------------
// blocks [0,1152): experts. 512 threads = 8 waves (2M x 4N), wave tile 128x64.
//   BM=256, BN=256, BK=64 x 8 tiles, double-buffered staging; tile-top vmcnt(0)+barrier
//   (loads had a full 4-phase tile to land); per-phase {4-8 ds_read -> setprio -> 16 MFMA ->
//   barrier} for wave role diversity. Phase barriers are scheduling-only (no race risk).
// blocks [1152,1408): gate path.
__global__ __launch_bounds__(512, 1) void k_expert_gate(
    const u16* __restrict__ xb, const u16* __restrict__ w1t, const u16* __restrict__ w2t,
    const float* __restrict__ sb1, const float* __restrict__ db1, const float* __restrict__ tb1,
    const float* __restrict__ sb2, const float* __restrict__ db2, const float* __restrict__ tb2,
    u16* __restrict__ eout,
    const u16* __restrict__ gw1t, const float* __restrict__ gb1,
    const float* __restrict__ gw2, const float* __restrict__ gb2, float* __restrict__ gates)
{
    // LDS: A buf c @ c*32768 (32KB: 256 rows x 128B), B buf c @ 65536 + c*32768 (32KB)
    //      GEMM2: hs [256][528B] @ 0 (135168 B, overlays everything)
    __shared__ __align__(128) char smem[135168];

    const int bid = blockIdx.x;
    const int tid = threadIdx.x;
    const int w = tid >> 6, lane = tid & 63;
    const int l15 = lane & 15, q = lane >> 4;
    const int q16 = q * 16;

    if (bid >= 1152) {
        // ================= GATE PATH (512 threads; MFMA on waves 0-3) =================
        u16* xs  = reinterpret_cast<u16*>(smem);
        u16* g1s = reinterpret_cast<u16*>(smem) + 4608;
        float* ghs = reinterpret_cast<float*>(smem);

        int m0 = (bid - 1152) * 64;
        int wm = w & 1, wn = (w >> 1) & 1;       // 2x2 grid over waves 0-3
        int lk = q * 8, lr4 = q * 4;

        f32x4 acc[2][6];
#pragma unroll
        for (int i = 0; i < 2; ++i)
#pragma unroll
            for (int j = 0; j < 6; ++j) acc[i][j] = (f32x4)0.f;

        const u16* xg = xb + (size_t)m0 * DIN;
        const int srow = tid >> 3, su = (tid & 7) * 8;   // srow 0..63
        for (int kc = 0; kc < DIN / 64; ++kc) {
            *reinterpret_cast<uint4*>(&xs[srow * 72 + su]) =
                *reinterpret_cast<const uint4*>(xg + (size_t)srow * DIN + kc * 64 + su);
#pragma unroll
            for (int it = 0; it < 3; ++it) {
                int rr = it * 64 + srow;
                *reinterpret_cast<uint4*>(&g1s[rr * 72 + su]) =
                    *reinterpret_cast<const uint4*>(gw1t + (size_t)rr * DIN + kc * 64 + su);
            }
            __syncthreads();
            if (w < 4) {
                s16x8 af[2][2], bfr[6][2];
#pragma unroll
                for (int mi = 0; mi < 2; ++mi)
#pragma unroll
                    for (int kk = 0; kk < 2; ++kk)
                        af[mi][kk] = *reinterpret_cast<const s16x8*>(&xs[(wm * 32 + mi * 16 + l15) * 72 + kk * 32 + lk]);
#pragma unroll
                for (int nj = 0; nj < 6; ++nj)
#pragma unroll
                    for (int kk = 0; kk < 2; ++kk)
                        bfr[nj][kk] = *reinterpret_cast<const s16x8*>(&g1s[(wn * 96 + nj * 16 + l15) * 72 + kk * 32 + lk]);
#pragma unroll
                for (int kk = 0; kk < 2; ++kk)
#pragma unroll
                    for (int mi = 0; mi < 2; ++mi)
#pragma unroll
                        for (int nj = 0; nj < 6; ++nj)
                            acc[mi][nj] = __builtin_amdgcn_mfma_f32_16x16x32_bf16(af[mi][kk], bfr[nj][kk], acc[mi][nj], 0, 0, 0);
            }
            __syncthreads();
        }
        if (w < 4) {
#pragma unroll
            for (int mi = 0; mi < 2; ++mi)
#pragma unroll
                for (int nj = 0; nj < 6; ++nj) {
                    int col = wn * 96 + nj * 16 + l15;
                    float bias = gb1[col];
#pragma unroll
                    for (int r = 0; r < 4; ++r) {
                        int row = wm * 32 + mi * 16 + lr4 + r;
                        float v = acc[mi][nj][r] + bias;
                        ghs[row * 200 + col] = v > 0.f ? v : 0.f;
                    }
                }
        }
        __syncthreads();

        if (tid < 192) {
            int tt = tid >> 6, rr = tid & 63;
            float logit[NETOT];
#pragma unroll
            for (int e2 = 0; e2 < NETOT; ++e2) logit[e2] = gb2[tt * NETOT + e2];
            const float* g2 = gw2 + tt * NGH * NETOT;
            const float* gr = &ghs[rr * 200 + tt * 64];
            for (int g = 0; g < NGH; ++g) {
                float v = gr[g];
#pragma unroll
                for (int e2 = 0; e2 < NETOT; ++e2) logit[e2] += v * g2[g * NETOT + e2];
            }
            float m = logit[0];
#pragma unroll
            for (int e2 = 1; e2 < NETOT; ++e2) m = fmaxf(m, logit[e2]);
            float s = 0.f, p[NETOT];
#pragma unroll
            for (int e2 = 0; e2 < NETOT; ++e2) { p[e2] = __expf(logit[e2] - m); s += p[e2]; }
            float inv = 1.f / s;
            float* go = gates + (size_t)(m0 + rr) * (NT * NETOT) + tt * NETOT;
#pragma unroll
            for (int e2 = 0; e2 < NETOT; ++e2) go[e2] = p[e2] * inv;
        }
        return;
    }

    // ================= EXPERT PATH =================
    const int e  = bid >> 6;
    const int m0 = (bid & 63) * 256;
    const int wm = w >> 2, wn = w & 3;           // 2M x 4N

    const u16* xg  = xb + (size_t)m0 * DIN;
    const u16* w1g = w1t + (size_t)e * H1 * DIN;
    const u16* w2g = w2t + (size_t)e * H2 * H1;
    const float* b1p = (e < 4) ? sb1 + e * H1 : (e < 12) ? db1 + (e - 4) * H1 : tb1 + (e - 12) * H1;
    const float* b2p = (e < 4) ? sb2 + e * H2 : (e < 12) ? db2 + (e - 4) * H2 : tb2 + (e - 12) * H2;

    // staging: 8 GLDS16/thread per K-tile (4 A + 4 B). 128B rows, pre-swizzled source.
    const int srow8 = lane >> 3, sslot = lane & 7;
    const u16* gxa[4]; const u16* gxb[4]; int lxa[4], lxb[4];
#pragma unroll
    for (int j = 0; j < 4; ++j) {
        int baserow = w * 32 + j * 8, row = baserow + srow8;
        gxa[j] = xg  + (size_t)row * DIN + ((sslot ^ (row & 7)) * 8);
        gxb[j] = w1g + (size_t)row * DIN + ((sslot ^ (row & 7)) * 8);
        lxa[j] = baserow * 128;                  // + buf*32768
        lxb[j] = 65536 + baserow * 128;          // + buf*32768
    }

    // fragment bases
    int offX[8], swA[8], offW[4], swB[4];
#pragma unroll
    for (int mi = 0; mi < 8; ++mi) {
        int r = wm * 128 + mi * 16 + l15;
        offX[mi] = r * 128; swA[mi] = (r & 7) << 4;
    }
#pragma unroll
    for (int nj = 0; nj < 4; ++nj) {
        int n = wn * 64 + nj * 16 + l15;
        offW[nj] = 65536 + n * 128; swB[nj] = (n & 7) << 4;
    }

    f32x4 acc1[8][4];
#pragma unroll
    for (int i = 0; i < 8; ++i)
#pragma unroll
        for (int j = 0; j < 4; ++j) acc1[i][j] = (f32x4)0.f;

    // ---- GEMM1: h[256,256] = x[256,512] @ W1t^T, 8 K-tiles of BK=64, 4 phases each ----
#pragma unroll
    for (int j = 0; j < 4; ++j) GLDS16(gxa[j], smem + lxa[j]);
#pragma unroll
    for (int j = 0; j < 4; ++j) GLDS16(gxb[j], smem + lxb[j]);

    int buf = 0;
    for (int kt = 0; kt < 8; ++kt) {
        VMCNT0_BARRIER();                        // tile-kt data resident (issued a full tile ago)
        if (kt < 7) {
            const int nb = (buf ^ 1) * 32768, ko = (kt + 1) * 64;
#pragma unroll
            for (int j = 0; j < 4; ++j) GLDS16(gxa[j] + ko, smem + nb + lxa[j]);
#pragma unroll
            for (int j = 0; j < 4; ++j) GLDS16(gxb[j] + ko, smem + nb + lxb[j]);
        }
        const int cb = buf * 32768;
#pragma unroll
        for (int kk = 0; kk < 2; ++kk) {
            const int kb = kk * 64 + q16;
            s16x8 wf[4];
#pragma unroll
            for (int nj = 0; nj < 4; ++nj)
                wf[nj] = *(const s16x8*)(smem + cb + offW[nj] + (kb ^ swB[nj]));
            // phase (kk, mh=0)
            {
                s16x8 xf[4];
#pragma unroll
                for (int i = 0; i < 4; ++i)
                    xf[i] = *(const s16x8*)(smem + cb + offX[i] + (kb ^ swA[i]));
                __builtin_amdgcn_s_setprio(1);
#pragma unroll
                for (int i = 0; i < 4; ++i)
#pragma unroll
                    for (int nj = 0; nj < 4; ++nj)
                        acc1[i][nj] = __builtin_amdgcn_mfma_f32_16x16x32_bf16(wf[nj], xf[i], acc1[i][nj], 0, 0, 0);
                __builtin_amdgcn_s_setprio(0);
            }
            __builtin_amdgcn_s_barrier();        // scheduling-only
            // phase (kk, mh=1)
            {
                s16x8 xf[4];
#pragma unroll
                for (int i = 0; i < 4; ++i)
                    xf[i] = *(const s16x8*)(smem + cb + offX[4 + i] + (kb ^ swA[4 + i]));
                __builtin_amdgcn_s_setprio(1);
#pragma unroll
                for (int i = 0; i < 4; ++i)
#pragma unroll
                    for (int nj = 0; nj < 4; ++nj)
                        acc1[4 + i][nj] = __builtin_amdgcn_mfma_f32_16x16x32_bf16(wf[nj], xf[i], acc1[4 + i][nj], 0, 0, 0);
                __builtin_amdgcn_s_setprio(0);
            }
            if (kk == 0) __builtin_amdgcn_s_barrier();   // scheduling-only
        }
        buf ^= 1;
    }
    __syncthreads();   // all reads of staging done before hs overlay

    // ---- h = relu(acc1 + b1) -> hs [256 rows][528 B] (padded rows) ----
#pragma unroll
    for (int mi = 0; mi < 8; ++mi) {
        const int m = wm * 128 + mi * 16 + l15;
        char* rowp = smem + m * 528;
#pragma unroll
        for (int nj = 0; nj < 4; ++nj) {
            const int n0 = wn * 64 + nj * 16 + q * 4;
            const float4 bv = *reinterpret_cast<const float4*>(b1p + n0);
            float v0 = fmaxf(acc1[mi][nj][0] + bv.x, 0.f);
            float v1 = fmaxf(acc1[mi][nj][1] + bv.y, 0.f);
            float v2 = fmaxf(acc1[mi][nj][2] + bv.z, 0.f);
            float v3 = fmaxf(acc1[mi][nj][3] + bv.w, 0.f);
            uint2 hv; hv.x = cvtpk(v0, v1); hv.y = cvtpk(v2, v3);
            *reinterpret_cast<uint2*>(rowp + n0 * 2) = hv;
        }
    }
    __syncthreads();

    // ---- GEMM2: o[256,128] = h[256,256] @ W2t^T; W2 from global; no barriers ----
    f32x4 acc2[8][2];
#pragma unroll
    for (int i = 0; i < 8; ++i)
#pragma unroll
        for (int j = 0; j < 2; ++j) acc2[i][j] = (f32x4)0.f;
    const u16* w2p0 = w2g + (size_t)(wn * 32 + l15) * H1 + q * 8;
    const u16* w2p1 = w2g + (size_t)(wn * 32 + 16 + l15) * H1 + q * 8;
#pragma unroll
    for (int kt2 = 0; kt2 < 8; ++kt2) {
        s16x8 wf2[2], hf[8];
        wf2[0] = *(const s16x8*)(w2p0 + kt2 * 32);
        wf2[1] = *(const s16x8*)(w2p1 + kt2 * 32);
#pragma unroll
        for (int mi = 0; mi < 8; ++mi)
            hf[mi] = *(const s16x8*)(smem + (wm * 128 + mi * 16 + l15) * 528 + kt2 * 64 + q16);
#pragma unroll
        for (int mi = 0; mi < 8; ++mi)
#pragma unroll
            for (int pj = 0; pj < 2; ++pj)
                acc2[mi][pj] = __builtin_amdgcn_mfma_f32_16x16x32_bf16(hf[mi], wf2[pj], acc2[mi][pj], 0, 0, 0);
    }

    // ---- epilogue: relu(acc2 + b2) -> eout[e][b][h] bf16 ----
    u16* eo = eout + ((size_t)e * NB + m0) * H2;
#pragma unroll
    for (int mi = 0; mi < 8; ++mi)
#pragma unroll
        for (int pj = 0; pj < 2; ++pj) {
            const int p = wn * 32 + pj * 16 + l15;
            const float bias = b2p[p];
#pragma unroll
            for (int r = 0; r < 4; ++r) {
                const int row = wm * 128 + mi * 16 + q * 4 + r;
                float v = acc2[mi][pj][r] + bias;
                eo[(size_t)row * H2 + p] = f2bf(v > 0.f ? v : 0.f);
            }
        }
}

// ---------------- combine ----------------
__global__ __launch_bounds__(256) void k_combine(
    const u16* __restrict__ eout, const float* __restrict__ gates, float* __restrict__ out)
{
    int tid = threadIdx.x;
    int lr = tid >> 5, hq = tid & 31;
    int b = blockIdx.x * 8 + lr;
    int h0 = hq * 4;
    const float* g = gates + (size_t)b * (NT * NETOT);
    float o0[4] = {0, 0, 0, 0}, o1[4] = {0, 0, 0, 0}, o2[4] = {0, 0, 0, 0};
#pragma unroll
    for (int e = 0; e < NE; ++e) {
        ushort4 ev = *reinterpret_cast<const ushort4*>(&eout[((size_t)e * NB + b) * H2 + h0]);
        float v0 = bf2f(ev.x), v1 = bf2f(ev.y), v2 = bf2f(ev.z), v3 = bf2f(ev.w);
        if (e < 12) {
            float wa = g[e], wb = g[NETOT + e], wc = g[2 * NETOT + e];
            o0[0] += wa * v0; o0[1] += wa * v1; o0[2] += wa * v2; o0[3] += wa * v3;
            o1[0] += wb * v0; o1[1] += wb * v1; o1[2] += wb * v2; o1[3] += wb * v3;
            o2[0] += wc * v0; o2[1] += wc * v1; o2[2] += wc * v2; o2[3] += wc * v3;
        } else {
            int t = (e - 12) >> 1, te = (e - 12) & 1;
            float wt = g[t * NETOT + 12 + te];
            float* ot = (t == 0) ? o0 : (t == 1) ? o1 : o2;
            ot[0] += wt * v0; ot[1] += wt * v1; ot[2] += wt * v2; ot[3] += wt * v3;
        }
    }
    size_t base = (size_t)b * H2 + h0;
    *reinterpret_cast<float4*>(&out[0 * (size_t)NB * H2 + base]) = make_float4(o0[0], o0[1], o0[2], o0[3]);
    *reinterpret_cast<float4*>(&out[1 * (size_t)NB * H2 + base]) = make_float4(o1[0], o1[1], o1[2], o1[3]);
    *reinterpret_cast<float4*>(&out[2 * (size_t)NB * H2 + base]) = make_float4(o2[0], o2[1], o2[2], o2[3]);
}

extern "C" void kernel_launch(void* const* d_in, const int* in_sizes, int n_in,
                              void* d_out, int out_size, void* d_ws, size_t ws_size,
                              hipStream_t stream)
{
    const float* x   = (const float*)d_in[0];
    const float* sW1 = (const float*)d_in[2];
    const float* sb1 = (const float*)d_in[3];
    const float* sW2 = (const float*)d_in[4];
    const float* sb2 = (const float*)d_in[5];
    const float* dW1 = (const float*)d_in[6];
    const float* db1 = (const float*)d_in[7];
    const float* dW2 = (const float*)d_in[8];
    const float* db2 = (const float*)d_in[9];
    const float* tW1 = (const float*)d_in[10];
    const float* tb1 = (const float*)d_in[11];
    const float* tW2 = (const float*)d_in[12];
    const float* tb2 = (const float*)d_in[13];
    const float* gW1 = (const float*)d_in[14];
    const float* gb1 = (const float*)d_in[15];
    const float* gW2 = (const float*)d_in[16];
    const float* gb2 = (const float*)d_in[17];

    char* ws = (char*)d_ws;
    u16*  xb    = (u16*)(ws + 0);
    u16*  w1t   = (u16*)(ws + 16777216);
    u16*  w2t   = (u16*)(ws + 21495808);
    u16*  gw1t  = (u16*)(ws + 22675456);
    float* gates = (float*)(ws + 22872064);
    u16*  eout  = (u16*)(ws + 25624576);

    k_prep<<<dim3(8936), dim3(256), 0, stream>>>(x, xb, sW1, dW1, tW1, sW2, dW2, tW2, gW1, w1t, w2t, gw1t);
    k_expert_gate<<<dim3(1408), dim3(512), 0, stream>>>(xb, w1t, w2t, sb1, db1, tb1, sb2, db2, tb2,
                                                        eout, gw1t, gb1, gW2, gb2, gates);
    k_combine<<<dim3(NB / 8), dim3(256), 0, stream>>>(eout, gates, (float*)d_out);
}

// Round 12
// 151.963 us; speedup vs baseline: 1.0032x; 1.0032x over previous
//
#include <hip/hip_runtime.h>
#include <hip/hip_bf16.h>

#define NB 16384
#define DIN 512
#define H1 256
#define H2 128
#define NE 18
#define NT 3
#define NGH 64
#define NETOT 14

typedef float f32x4 __attribute__((ext_vector_type(4)));
typedef short s16x8 __attribute__((ext_vector_type(8)));
typedef unsigned short u16;
typedef unsigned int u32;

__device__ __forceinline__ u16 f2bf(float f) {
    union { float f; u32 u; } v; v.f = f;
    u32 r = v.u + 0x7fffu + ((v.u >> 16) & 1u);
    return (u16)(r >> 16);
}
__device__ __forceinline__ float bf2f(u16 u) {
    union { u32 u; float f; } v; v.u = ((u32)u) << 16;
    return v.f;
}
__device__ __forceinline__ u32 cvtpk(float a, float b) {
    u32 r;
    asm("v_cvt_pk_bf16_f32 %0, %1, %2" : "=v"(r) : "v"(a), "v"(b));
    return r;
}

#define GLDS16(g, l) __builtin_amdgcn_global_load_lds((const u32*)(g), (u32*)(l), 16, 0, 0)
#define VMW(n) asm volatile("s_waitcnt vmcnt(" #n ")" ::: "memory")

// ---------------- prep: x cvt + ALL weight transposes, one launch ----------------
__global__ __launch_bounds__(256) void k_prep(
    const float* __restrict__ x, u16* __restrict__ xb,
    const float* __restrict__ sW1, const float* __restrict__ dW1, const float* __restrict__ tW1,
    const float* __restrict__ sW2, const float* __restrict__ dW2, const float* __restrict__ tW2,
    const float* __restrict__ gW1, u16* __restrict__ w1t, u16* __restrict__ w2t, u16* __restrict__ gw1t)
{
    __shared__ float lds[64 * 65];
    int bx = blockIdx.x;
    if (bx < 8192) {
        int i = (bx * 256 + threadIdx.x) * 4;
        float4 v = *reinterpret_cast<const float4*>(x + i);
        ushort4 o;
        o.x = f2bf(v.x); o.y = f2bf(v.y); o.z = f2bf(v.z); o.w = f2bf(v.w);
        *reinterpret_cast<ushort4*>(xb + i) = o;
        return;
    }
    int b = bx - 8192;
    const float* src; u16* dst; int K, N, k0, n0;
    if (b < 576) {
        int e = b >> 5, tile = b & 31;
        src = (e < 4) ? sW1 + (size_t)e * DIN * H1 : (e < 12) ? dW1 + (size_t)(e - 4) * DIN * H1
                                                              : tW1 + (size_t)(e - 12) * DIN * H1;
        dst = w1t + (size_t)e * H1 * DIN; K = DIN; N = H1;
        k0 = (tile >> 2) * 64; n0 = (tile & 3) * 64;
    } else if (b < 720) {
        int b2 = b - 576; int e = b2 >> 3, tile = b2 & 7;
        src = (e < 4) ? sW2 + (size_t)e * H1 * H2 : (e < 12) ? dW2 + (size_t)(e - 4) * H1 * H2
                                                             : tW2 + (size_t)(e - 12) * H1 * H2;
        dst = w2t + (size_t)e * H2 * H1; K = H1; N = H2;
        k0 = (tile >> 1) * 64; n0 = (tile & 1) * 64;
    } else {
        int b3 = b - 720; int t = b3 >> 3, tile = b3 & 7;
        src = gW1 + (size_t)t * DIN * NGH; dst = gw1t + (size_t)t * NGH * DIN; K = DIN; N = NGH;
        k0 = tile * 64; n0 = 0;
    }
    int t = threadIdx.x;
#pragma unroll
    for (int i = 0; i < 16; ++i) {
        int idx = i * 256 + t;
        int kk = idx >> 6, nn = idx & 63;
        lds[kk * 65 + nn] = src[(size_t)(k0 + kk) * N + n0 + nn];
    }
    __syncthreads();
#pragma unroll
    for (int i = 0; i < 16; ++i) {
        int idx = i * 256 + t;
        int nn = idx >> 6, kk = idx & 63;
        dst[(size_t)(n0 + nn) * K + k0 + kk] = f2bf(lds[kk * 65 + nn]);
    }
}

// ---------------- fused expert (+gate) kernel: counted-wait phase schedule ----------------
// blocks [0,1152): experts. 512 threads = 8 waves (2M x 4N), wave tile 128x64.
//   BM=256, BN=256, BK=32 x 16 tiles, 4 LDS buffers (tile u -> buf u&3).
//   Per 2-tile iter: 4 phases of 16 MFMA; stages spread 2 GLDS/phase; uniform vmcnt(10)
//   counted gates at tile-entry phases (never drain-0 in steady state). 6-phase stage lead.
// blocks [1152,1408): gate path.
__global__ __launch_bounds__(512, 1) void k_expert_gate(
    const u16* __restrict__ xb, const u16* __restrict__ w1t, const u16* __restrict__ w2t,
    const float* __restrict__ sb1, const float* __restrict__ db1, const float* __restrict__ tb1,
    const float* __restrict__ sb2, const float* __restrict__ db2, const float* __restrict__ tb2,
    u16* __restrict__ eout,
    const u16* __restrict__ gw1t, const float* __restrict__ gb1,
    const float* __restrict__ gw2, const float* __restrict__ gb2, float* __restrict__ gates)
{
    // LDS: buf t (t=0..3) @ t*32768: A [256 rows][64B] (16KB), B @ +16384 (16KB). 128KB.
    //      GEMM2: hs [256][528B] @ 0 (135168 B, overlays everything)
    __shared__ __align__(128) char smem[135168];

    const int bid = blockIdx.x;
    const int tid = threadIdx.x;
    const int w = tid >> 6, lane = tid & 63;
    const int l15 = lane & 15, q = lane >> 4;
    const int q16 = q * 16;

    if (bid >= 1152) {
        // ================= GATE PATH (512 threads; MFMA on waves 0-3) =================
        u16* xs  = reinterpret_cast<u16*>(smem);
        u16* g1s = reinterpret_cast<u16*>(smem) + 4608;
        float* ghs = reinterpret_cast<float*>(smem);

        int m0 = (bid - 1152) * 64;
        int wm = w & 1, wn = (w >> 1) & 1;
        int lk = q * 8, lr4 = q * 4;

        f32x4 acc[2][6];
#pragma unroll
        for (int i = 0; i < 2; ++i)
#pragma unroll
            for (int j = 0; j < 6; ++j) acc[i][j] = (f32x4)0.f;

        const u16* xg = xb + (size_t)m0 * DIN;
        const int srow = tid >> 3, su = (tid & 7) * 8;
        for (int kc = 0; kc < DIN / 64; ++kc) {
            *reinterpret_cast<uint4*>(&xs[srow * 72 + su]) =
                *reinterpret_cast<const uint4*>(xg + (size_t)srow * DIN + kc * 64 + su);
#pragma unroll
            for (int it = 0; it < 3; ++it) {
                int rr = it * 64 + srow;
                *reinterpret_cast<uint4*>(&g1s[rr * 72 + su]) =
                    *reinterpret_cast<const uint4*>(gw1t + (size_t)rr * DIN + kc * 64 + su);
            }
            __syncthreads();
            if (w < 4) {
                s16x8 af[2][2], bfr[6][2];
#pragma unroll
                for (int mi = 0; mi < 2; ++mi)
#pragma unroll
                    for (int kk = 0; kk < 2; ++kk)
                        af[mi][kk] = *reinterpret_cast<const s16x8*>(&xs[(wm * 32 + mi * 16 + l15) * 72 + kk * 32 + lk]);
#pragma unroll
                for (int nj = 0; nj < 6; ++nj)
#pragma unroll
                    for (int kk = 0; kk < 2; ++kk)
                        bfr[nj][kk] = *reinterpret_cast<const s16x8*>(&g1s[(wn * 96 + nj * 16 + l15) * 72 + kk * 32 + lk]);
#pragma unroll
                for (int kk = 0; kk < 2; ++kk)
#pragma unroll
                    for (int mi = 0; mi < 2; ++mi)
#pragma unroll
                        for (int nj = 0; nj < 6; ++nj)
                            acc[mi][nj] = __builtin_amdgcn_mfma_f32_16x16x32_bf16(af[mi][kk], bfr[nj][kk], acc[mi][nj], 0, 0, 0);
            }
            __syncthreads();
        }
        if (w < 4) {
#pragma unroll
            for (int mi = 0; mi < 2; ++mi)
#pragma unroll
                for (int nj = 0; nj < 6; ++nj) {
                    int col = wn * 96 + nj * 16 + l15;
                    float bias = gb1[col];
#pragma unroll
                    for (int r = 0; r < 4; ++r) {
                        int row = wm * 32 + mi * 16 + lr4 + r;
                        float v = acc[mi][nj][r] + bias;
                        ghs[row * 200 + col] = v > 0.f ? v : 0.f;
                    }
                }
        }
        __syncthreads();

        if (tid < 192) {
            int tt = tid >> 6, rr = tid & 63;
            float logit[NETOT];
#pragma unroll
            for (int e2 = 0; e2 < NETOT; ++e2) logit[e2] = gb2[tt * NETOT + e2];
            const float* g2 = gw2 + tt * NGH * NETOT;
            const float* gr = &ghs[rr * 200 + tt * 64];
            for (int g = 0; g < NGH; ++g) {
                float v = gr[g];
#pragma unroll
                for (int e2 = 0; e2 < NETOT; ++e2) logit[e2] += v * g2[g * NETOT + e2];
            }
            float m = logit[0];
#pragma unroll
            for (int e2 = 1; e2 < NETOT; ++e2) m = fmaxf(m, logit[e2]);
            float s = 0.f, p[NETOT];
#pragma unroll
            for (int e2 = 0; e2 < NETOT; ++e2) { p[e2] = __expf(logit[e2] - m); s += p[e2]; }
            float inv = 1.f / s;
            float* go = gates + (size_t)(m0 + rr) * (NT * NETOT) + tt * NETOT;
#pragma unroll
            for (int e2 = 0; e2 < NETOT; ++e2) go[e2] = p[e2] * inv;
        }
        return;
    }

    // ================= EXPERT PATH =================
    const int e  = bid >> 6;
    const int m0 = (bid & 63) * 256;
    const int wm = w >> 2, wn = w & 3;           // 2M x 4N

    const u16* xg  = xb + (size_t)m0 * DIN;
    const u16* w1g = w1t + (size_t)e * H1 * DIN;
    const u16* w2g = w2t + (size_t)e * H2 * H1;
    const float* b1p = (e < 4) ? sb1 + e * H1 : (e < 12) ? db1 + (e - 4) * H1 : tb1 + (e - 12) * H1;
    const float* b2p = (e < 4) ? sb2 + e * H2 : (e < 12) ? db2 + (e - 4) * H2 : tb2 + (e - 12) * H2;

    // ---- staging (64B rows; lane -> row base+(lane>>2), slot lane&3; pre-swizzled source) ----
    const int srow4 = lane >> 2, scol = lane & 3;
    const u16* gA[2]; const u16* gB[2]; int lA[2], lB[2];
#pragma unroll
    for (int s = 0; s < 2; ++s) {
        int row = s * 128 + w * 16 + srow4;
        int sw = (scol ^ ((row >> 1) & 3)) * 8;
        gA[s] = xg  + (size_t)row * DIN + sw;
        gB[s] = w1g + (size_t)row * DIN + sw;
        lA[s] = s * 8192 + w * 1024;
        lB[s] = 16384 + s * 8192 + w * 1024;
    }

    // ---- per-lane fragment read offsets (within a buffer) ----
    int roffX[8], roffW[4];
#pragma unroll
    for (int mi = 0; mi < 8; ++mi) {
        int r = wm * 128 + mi * 16 + l15;
        roffX[mi] = r * 64 + (q16 ^ (((r >> 1) & 3) << 4));
    }
#pragma unroll
    for (int nj = 0; nj < 4; ++nj) {
        int n = wn * 64 + nj * 16 + l15;
        roffW[nj] = 16384 + n * 64 + (q16 ^ (((n >> 1) & 3) << 4));
    }

    f32x4 acc1[8][4];
#pragma unroll
    for (int i = 0; i < 8; ++i)
#pragma unroll
        for (int j = 0; j < 4; ++j) acc1[i][j] = (f32x4)0.f;

    // ---- prologue: stage tiles 0,1,2 (12 GLDS) ----
#pragma unroll
    for (int u = 0; u < 3; ++u) {
        const int ub = u * 32768, ko = u * 32;
        GLDS16(gA[0] + ko, smem + ub + lA[0]); GLDS16(gA[1] + ko, smem + ub + lA[1]);
        GLDS16(gB[0] + ko, smem + ub + lB[0]); GLDS16(gB[1] + ko, smem + ub + lB[1]);
    }

    // ---- GEMM1 main loop: 8 iters x {4 phases}, tiles T0=2i (buf 2i&3), T1=2i+1 ----
#pragma unroll
    for (int i = 0; i < 8; ++i) {
        const int cb0 = ((2 * i) & 3) * 32768;
        const int cb1 = ((2 * i + 1) & 3) * 32768;
        s16x8 af[8], bf[4];

        // ---- phase 0: stage A(2i+3); gate T0 (counted); read T0; MFMA mh0 ----
        if (i <= 6) {
            const int u = 2 * i + 3, ub = (u & 3) * 32768, ko = u * 32;
            GLDS16(gA[0] + ko, smem + ub + lA[0]); GLDS16(gA[1] + ko, smem + ub + lA[1]);
        }
        if (i < 7) { VMW(10); } else { VMW(4); }
        __builtin_amdgcn_s_barrier();
#pragma unroll
        for (int mi = 0; mi < 8; ++mi) af[mi] = *(const s16x8*)(smem + cb0 + roffX[mi]);
#pragma unroll
        for (int nj = 0; nj < 4; ++nj) bf[nj] = *(const s16x8*)(smem + cb0 + roffW[nj]);
        __builtin_amdgcn_s_setprio(1);
#pragma unroll
        for (int mi = 0; mi < 4; ++mi)
#pragma unroll
            for (int nj = 0; nj < 4; ++nj)
                acc1[mi][nj] = __builtin_amdgcn_mfma_f32_16x16x32_bf16(bf[nj], af[mi], acc1[mi][nj], 0, 0, 0);
        __builtin_amdgcn_s_setprio(0);
        __builtin_amdgcn_s_barrier();

        // ---- phase 1: stage B(2i+3); pure MFMA mh1 ----
        if (i <= 6) {
            const int u = 2 * i + 3, ub = (u & 3) * 32768, ko = u * 32;
            GLDS16(gB[0] + ko, smem + ub + lB[0]); GLDS16(gB[1] + ko, smem + ub + lB[1]);
        }
        __builtin_amdgcn_s_barrier();
        __builtin_amdgcn_s_setprio(1);
#pragma unroll
        for (int mi = 0; mi < 4; ++mi)
#pragma unroll
            for (int nj = 0; nj < 4; ++nj)
                acc1[4 + mi][nj] = __builtin_amdgcn_mfma_f32_16x16x32_bf16(bf[nj], af[4 + mi], acc1[4 + mi][nj], 0, 0, 0);
        __builtin_amdgcn_s_setprio(0);
        __builtin_amdgcn_s_barrier();

        // ---- phase 2: stage A(2i+4); gate T1 (counted); read T1; MFMA mh0 ----
        if (i <= 5) {
            const int u = 2 * i + 4, ub = (u & 3) * 32768, ko = u * 32;
            GLDS16(gA[0] + ko, smem + ub + lA[0]); GLDS16(gA[1] + ko, smem + ub + lA[1]);
        }
        if (i < 6) { VMW(10); } else if (i == 6) { VMW(8); } else { VMW(0); }
        __builtin_amdgcn_s_barrier();
#pragma unroll
        for (int mi = 0; mi < 8; ++mi) af[mi] = *(const s16x8*)(smem + cb1 + roffX[mi]);
#pragma unroll
        for (int nj = 0; nj < 4; ++nj) bf[nj] = *(const s16x8*)(smem + cb1 + roffW[nj]);
        __builtin_amdgcn_s_setprio(1);
#pragma unroll
        for (int mi = 0; mi < 4; ++mi)
#pragma unroll
            for (int nj = 0; nj < 4; ++nj)
                acc1[mi][nj] = __builtin_amdgcn_mfma_f32_16x16x32_bf16(bf[nj], af[mi], acc1[mi][nj], 0, 0, 0);
        __builtin_amdgcn_s_setprio(0);
        __builtin_amdgcn_s_barrier();

        // ---- phase 3: stage B(2i+4); pure MFMA mh1 ----
        if (i <= 5) {
            const int u = 2 * i + 4, ub = (u & 3) * 32768, ko = u * 32;
            GLDS16(gB[0] + ko, smem + ub + lB[0]); GLDS16(gB[1] + ko, smem + ub + lB[1]);
        }
        __builtin_amdgcn_s_barrier();
        __builtin_amdgcn_s_setprio(1);
#pragma unroll
        for (int mi = 0; mi < 4; ++mi)
#pragma unroll
            for (int nj = 0; nj < 4; ++nj)
                acc1[4 + mi][nj] = __builtin_amdgcn_mfma_f32_16x16x32_bf16(bf[nj], af[4 + mi], acc1[4 + mi][nj], 0, 0, 0);
        __builtin_amdgcn_s_setprio(0);
        __builtin_amdgcn_s_barrier();
    }
    __syncthreads();   // all staging reads done before hs overlay write

    // ---- h = relu(acc1 + b1) -> hs [256 rows][528 B] (padded rows) ----
#pragma unroll
    for (int mi = 0; mi < 8; ++mi) {
        const int m = wm * 128 + mi * 16 + l15;
        char* rowp = smem + m * 528;
#pragma unroll
        for (int nj = 0; nj < 4; ++nj) {
            const int n0 = wn * 64 + nj * 16 + q * 4;
            const float4 bv = *reinterpret_cast<const float4*>(b1p + n0);
            float v0 = fmaxf(acc1[mi][nj][0] + bv.x, 0.f);
            float v1 = fmaxf(acc1[mi][nj][1] + bv.y, 0.f);
            float v2 = fmaxf(acc1[mi][nj][2] + bv.z, 0.f);
            float v3 = fmaxf(acc1[mi][nj][3] + bv.w, 0.f);
            uint2 hv; hv.x = cvtpk(v0, v1); hv.y = cvtpk(v2, v3);
            *reinterpret_cast<uint2*>(rowp + n0 * 2) = hv;
        }
    }
    __syncthreads();

    // ---- GEMM2: o[256,128] = h[256,256] @ W2t^T; W2 from global; no barriers ----
    f32x4 acc2[8][2];
#pragma unroll
    for (int i = 0; i < 8; ++i)
#pragma unroll
        for (int j = 0; j < 2; ++j) acc2[i][j] = (f32x4)0.f;
    const u16* w2p0 = w2g + (size_t)(wn * 32 + l15) * H1 + q * 8;
    const u16* w2p1 = w2g + (size_t)(wn * 32 + 16 + l15) * H1 + q * 8;
#pragma unroll
    for (int kt2 = 0; kt2 < 8; ++kt2) {
        s16x8 wf2[2], hf[8];
        wf2[0] = *(const s16x8*)(w2p0 + kt2 * 32);
        wf2[1] = *(const s16x8*)(w2p1 + kt2 * 32);
#pragma unroll
        for (int mi = 0; mi < 8; ++mi)
            hf[mi] = *(const s16x8*)(smem + (wm * 128 + mi * 16 + l15) * 528 + kt2 * 64 + q16);
#pragma unroll
        for (int mi = 0; mi < 8; ++mi)
#pragma unroll
            for (int pj = 0; pj < 2; ++pj)
                acc2[mi][pj] = __builtin_amdgcn_mfma_f32_16x16x32_bf16(hf[mi], wf2[pj], acc2[mi][pj], 0, 0, 0);
    }

    // ---- epilogue: relu(acc2 + b2) -> eout[e][b][h] bf16 ----
    u16* eo = eout + ((size_t)e * NB + m0) * H2;
#pragma unroll
    for (int mi = 0; mi < 8; ++mi)
#pragma unroll
        for (int pj = 0; pj < 2; ++pj) {
            const int p = wn * 32 + pj * 16 + l15;
            const float bias = b2p[p];
#pragma unroll
            for (int r = 0; r < 4; ++r) {
                const int row = wm * 128 + mi * 16 + q * 4 + r;
                float v = acc2[mi][pj][r] + bias;
                eo[(size_t)row * H2 + p] = f2bf(v > 0.f ? v : 0.f);
            }
        }
}

// ---------------- combine ----------------
__global__ __launch_bounds__(256) void k_combine(
    const u16* __restrict__ eout, const float* __restrict__ gates, float* __restrict__ out)
{
    int tid = threadIdx.x;
    int lr = tid >> 5, hq = tid & 31;
    int b = blockIdx.x * 8 + lr;
    int h0 = hq * 4;
    const float* g = gates + (size_t)b * (NT * NETOT);
    float o0[4] = {0, 0, 0, 0}, o1[4] = {0, 0, 0, 0}, o2[4] = {0, 0, 0, 0};
#pragma unroll
    for (int e = 0; e < NE; ++e) {
        ushort4 ev = *reinterpret_cast<const ushort4*>(&eout[((size_t)e * NB + b) * H2 + h0]);
        float v0 = bf2f(ev.x), v1 = bf2f(ev.y), v2 = bf2f(ev.z), v3 = bf2f(ev.w);
        if (e < 12) {
            float wa = g[e], wb = g[NETOT + e], wc = g[2 * NETOT + e];
            o0[0] += wa * v0; o0[1] += wa * v1; o0[2] += wa * v2; o0[3] += wa * v3;
            o1[0] += wb * v0; o1[1] += wb * v1; o1[2] += wb * v2; o1[3] += wb * v3;
            o2[0] += wc * v0; o2[1] += wc * v1; o2[2] += wc * v2; o2[3] += wc * v3;
        } else {
            int t = (e - 12) >> 1, te = (e - 12) & 1;
            float wt = g[t * NETOT + 12 + te];
            float* ot = (t == 0) ? o0 : (t == 1) ? o1 : o2;
            ot[0] += wt * v0; ot[1] += wt * v1; ot[2] += wt * v2; ot[3] += wt * v3;
        }
    }
    size_t base = (size_t)b * H2 + h0;
    *reinterpret_cast<float4*>(&out[0 * (size_t)NB * H2 + base]) = make_float4(o0[0], o0[1], o0[2], o0[3]);
    *reinterpret_cast<float4*>(&out[1 * (size_t)NB * H2 + base]) = make_float4(o1[0], o1[1], o1[2], o1[3]);
    *reinterpret_cast<float4*>(&out[2 * (size_t)NB * H2 + base]) = make_float4(o2[0], o2[1], o2[2], o2[3]);
}

extern "C" void kernel_launch(void* const* d_in, const int* in_sizes, int n_in,
                              void* d_out, int out_size, void* d_ws, size_t ws_size,
                              hipStream_t stream)
{
    const float* x   = (const float*)d_in[0];
    const float* sW1 = (const float*)d_in[2];
    const float* sb1 = (const float*)d_in[3];
    const float* sW2 = (const float*)d_in[4];
    const float* sb2 = (const float*)d_in[5];
    const float* dW1 = (const float*)d_in[6];
    const float* db1 = (const float*)d_in[7];
    const float* dW2 = (const float*)d_in[8];
    const float* db2 = (const float*)d_in[9];
    const float* tW1 = (const float*)d_in[10];
    const float* tb1 = (const float*)d_in[11];
    const float* tW2 = (const float*)d_in[12];
    const float* tb2 = (const float*)d_in[13];
    const float* gW1 = (const float*)d_in[14];
    const float* gb1 = (const float*)d_in[15];
    const float* gW2 = (const float*)d_in[16];
    const float* gb2 = (const float*)d_in[17];

    char* ws = (char*)d_ws;
    u16*  xb    = (u16*)(ws + 0);
    u16*  w1t   = (u16*)(ws + 16777216);
    u16*  w2t   = (u16*)(ws + 21495808);
    u16*  gw1t  = (u16*)(ws + 22675456);
    float* gates = (float*)(ws + 22872064);
    u16*  eout  = (u16*)(ws + 25624576);

    k_prep<<<dim3(8936), dim3(256), 0, stream>>>(x, xb, sW1, dW1, tW1, sW2, dW2, tW2, gW1, w1t, w2t, gw1t);
    k_expert_gate<<<dim3(1408), dim3(512), 0, stream>>>(xb, w1t, w2t, sb1, db1, tb1, sb2, db2, tb2,
                                                        eout, gw1t, gb1, gW2, gb2, gates);
    k_combine<<<dim3(NB / 8), dim3(256), 0, stream>>>(eout, gates, (float*)d_out);
}